// Round 1
// baseline (1656.112 us; speedup 1.0000x reference)
//
#include <hip/hip_runtime.h>
#include <hip/hip_bf16.h>
#include <math.h>

typedef __attribute__((ext_vector_type(8))) short short8;
typedef __attribute__((ext_vector_type(4))) float f32x4;
typedef unsigned short u16;
typedef unsigned int u32;

#define DEV __device__ __forceinline__

DEV float bf2f(u16 u){ u32 x = ((u32)u)<<16; return __builtin_bit_cast(float, x); }
DEV u16 f2bf(float f){ u32 x = __builtin_bit_cast(u32, f); return (u16)((x + 0x7FFFu + ((x>>16)&1u))>>16); }
DEV f32x4 mfma16(short8 a, short8 b, f32x4 c){ return __builtin_amdgcn_mfma_f32_16x16x32_bf16(a,b,c,0,0,0); }
DEV void gload16(const void* g, void* l){
  __builtin_amdgcn_global_load_lds((const __attribute__((address_space(1))) void*)g,
                                   (__attribute__((address_space(3))) void*)l, 16, 0, 0);
}
DEV u32 fkey(float f){ u32 b = __builtin_bit_cast(u32, f); return (b & 0x80000000u) ? ~b : (b ^ 0x80000000u); }
DEV float funkey(u32 k){ u32 b = (k & 0x80000000u) ? (k ^ 0x80000000u) : ~k; return __builtin_bit_cast(float, b); }

// ---------------- workspace layout (bytes) ----------------
static constexpr size_t O_PROJW = 0;                         // 512*512*2
static constexpr size_t O_QKVW  = O_PROJW + 524288;          // 6*1536*512*2
static constexpr size_t O_WOW   = O_QKVW + 9437184;          // 6*512*512*2
static constexpr size_t O_W1W   = O_WOW + 3145728;
static constexpr size_t O_W2W   = O_W1W + 3145728;
static constexpr size_t O_C1W   = O_W2W + 3145728;           // 128*2880*2
static constexpr size_t O_C2W   = O_C1W + 737280;            // 320*1152*2
static constexpr size_t O_RA    = O_C2W + 737280;            // pcl1 22.3MB / tmp f32 / pcl2
static constexpr size_t O_RB    = O_RA + 22302720;           // patches f32 16.8MB then qkv bf16 25.2MB
static constexpr size_t O_X     = O_RB + 25165824;           // x f32 16.8MB
static constexpr size_t O_D     = O_X + 16777216;            // xn bf16 8.4MB
static constexpr size_t O_F     = O_D + 8388608;             // o/g bf16 8.4MB
static constexpr size_t O_RM    = O_F + 8388608;             // 48*1024 u8
static constexpr size_t O_MIN   = O_RM + 49152;              // 6 u32 keys
static constexpr size_t WS_NEED = O_MIN + 256;

// ---------------- weight conversion ----------------
// src [z][K][N] f32 -> dst [z][N][K] bf16
__global__ __launch_bounds__(256) void k_transpose_bf(const float* __restrict__ src, u16* __restrict__ dst, int K, int N){
  __shared__ float tile[32][33];
  const int k0 = blockIdx.x*32, n0 = blockIdx.y*32;
  src += (size_t)blockIdx.z*K*N; dst += (size_t)blockIdx.z*K*N;
  const int c = threadIdx.x & 31, r4 = threadIdx.x >> 5;
  for(int r=r4; r<32; r+=8) tile[r][c] = src[(size_t)(k0+r)*N + n0+c];
  __syncthreads();
  for(int r=r4; r<32; r+=8) dst[(size_t)(n0+r)*K + k0+c] = f2bf(tile[c][r]);
}

// conv weights [OC][IC][3][3] f32 -> Wt [OC][tap*IC+ic] bf16
__global__ __launch_bounds__(256) void k_convw(const float* __restrict__ src, u16* __restrict__ dst, int OC, int IC){
  int idx = blockIdx.x*256 + threadIdx.x;
  int total = OC*IC*9;
  if(idx >= total) return;
  int oc = idx/(IC*9); int rem = idx - oc*IC*9; int tap = rem/IC; int ic = rem - tap*IC;
  dst[idx] = f2bf(src[(size_t)(oc*IC+ic)*9 + tap]);
}

// img [8][320][64][64] f32 -> pcl1 [8][66][66][320] bf16 (interior; borders pre-zeroed)
__global__ __launch_bounds__(256) void k_pad_img(const float* __restrict__ img, u16* __restrict__ pcl){
  const int by = blockIdx.x; const int b = by>>6, y = by&63; const int c0 = blockIdx.y*64;
  __shared__ float t[64][65];
  const int tx = threadIdx.x & 63, tz = threadIdx.x >> 6;
  for(int ci=tz; ci<64; ci+=4) t[ci][tx] = img[(((size_t)b*320 + c0+ci)*64 + y)*64 + tx];
  __syncthreads();
  for(int x=tz; x<64; x+=4) pcl[(((size_t)b*66 + y+1)*66 + (x+1))*320 + c0 + tx] = f2bf(t[tx][x]);
}

// x tokens f32 -> pcl2 [8][66][66][128] bf16 (interior)
__global__ __launch_bounds__(256) void k_pad_tok(const float* __restrict__ x, u16* __restrict__ pcl){
  int idx = blockIdx.x*256 + threadIdx.x;           // 8*64*64*128
  const int c = idx & 127; int r = idx >> 7; const int xx = r & 63; r >>= 6; const int yy = r & 63; const int b = r >> 6;
  const int n = (yy>>1)*32 + (xx>>1); const int f = (yy&1)*256 + (xx&1)*128 + c;
  pcl[(((size_t)b*66 + yy+1)*66 + xx+1)*128 + c] = f2bf(x[((size_t)b*1024 + n)*512 + f]);
}

// mask [48][64][64] int -> rm [48][1024] u8 (2x2 any)
__global__ __launch_bounds__(256) void k_rmask(const int* __restrict__ mask, unsigned char* __restrict__ rm){
  int idx = blockIdx.x*256 + threadIdx.x;
  if(idx >= 48*1024) return;
  const int m = idx >> 10, n = idx & 1023; const int h = n>>5, w = n&31;
  const int* mp = mask + ((size_t)m*64 + h*2)*64 + w*2;
  rm[idx] = (unsigned char)((mp[0]==1) | (mp[1]==1) | (mp[64]==1) | (mp[65]==1));
}

// ---------------- layernorm ----------------
__global__ __launch_bounds__(256) void k_ln_bf(const float* __restrict__ in, const float* __restrict__ gw,
                                               const float* __restrict__ bw, u16* __restrict__ out){
  const int t = blockIdx.x, tid = threadIdx.x;
  const float2 v = *(const float2*)(in + (size_t)t*512 + tid*2);
  float s = v.x + v.y, sq = v.x*v.x + v.y*v.y;
  #pragma unroll
  for(int off=32; off; off>>=1){ s += __shfl_down(s,off); sq += __shfl_down(sq,off); }
  __shared__ float ps[4], pq[4];
  const int wv = tid>>6;
  if((tid&63)==0){ ps[wv]=s; pq[wv]=sq; }
  __syncthreads();
  s = ps[0]+ps[1]+ps[2]+ps[3]; sq = pq[0]+pq[1]+pq[2]+pq[3];
  const float mu = s*(1.f/512.f);
  const float rs = rsqrtf(sq*(1.f/512.f) - mu*mu + 1e-5f);
  out[(size_t)t*512 + tid*2]   = f2bf((v.x-mu)*rs*gw[tid*2]   + bw[tid*2]);
  out[(size_t)t*512 + tid*2+1] = f2bf((v.y-mu)*rs*gw[tid*2+1] + bw[tid*2+1]);
}

// LN + sincos 2d posemb -> f32 x
__global__ __launch_bounds__(256) void k_lnq_pos(const float* __restrict__ in, const float* __restrict__ gw,
                                                 const float* __restrict__ bw, float* __restrict__ out){
  const int t = blockIdx.x, tid = threadIdx.x;
  const float2 v = *(const float2*)(in + (size_t)t*512 + tid*2);
  float s = v.x + v.y, sq = v.x*v.x + v.y*v.y;
  #pragma unroll
  for(int off=32; off; off>>=1){ s += __shfl_down(s,off); sq += __shfl_down(sq,off); }
  __shared__ float ps[4], pq[4];
  const int wv = tid>>6;
  if((tid&63)==0){ ps[wv]=s; pq[wv]=sq; }
  __syncthreads();
  s = ps[0]+ps[1]+ps[2]+ps[3]; sq = pq[0]+pq[1]+pq[2]+pq[3];
  const float mu = s*(1.f/512.f);
  const float rs = rsqrtf(sq*(1.f/512.f) - mu*mu + 1e-5f);
  const int n = t & 1023; const int yy = n>>5, xx = n&31;
  #pragma unroll
  for(int j=0;j<2;j++){
    const int f = tid*2+j;
    const float ln = ((j==0?v.x:v.y)-mu)*rs*gw[f] + bw[f];
    const int q = f & 127, sec = f >> 7;
    const float om = expf(-(float)q * (9.2103403719761836f/127.f));  // ln(10000)
    const float arg = (sec<2 ? (float)xx : (float)yy) * om;
    const float pe = (sec&1) ? cosf(arg) : sinf(arg);
    out[(size_t)t*512 + f] = ln + pe;
  }
}

// ---------------- GEMM (128x128 tile, BK=32, 4 waves, global_load_lds) ----------------
// EPI: 0 proj(f32+bias) 1 qkv-scatter(bf16) 2 resid(f32) 3 gelu(bf16+bias) 4 resid+bias 5 conv1->patches 6 conv2->out
template<int EPI, int CONVC>
__global__ __launch_bounds__(256)
void k_gemm(const u16* __restrict__ A, const u16* __restrict__ Wt,
            const float* __restrict__ bias, void* __restrict__ outp,
            const float* __restrict__ resid, int M, int N, int Kd)
{
  __shared__ u16 Ald[128*32];
  __shared__ u16 Bld[128*32];
  const int tid = threadIdx.x, lane = tid & 63, wv = tid >> 6;
  const int lr = lane & 15, g = lane >> 4;
  const int m0 = blockIdx.x * 128, n0 = blockIdx.y * 128;
  const int wm = (wv >> 1) * 64, wn = (wv & 1) * 64;
  const int arow0 = wv*32 + (lane>>2);
  const int arow1 = arow0 + 16;
  const int acol = (lane & 3) * 8;
  u16* lA0 = &Ald[(wv*2+0)*512]; u16* lA1 = &Ald[(wv*2+1)*512];
  u16* lB0 = &Bld[(wv*2+0)*512]; u16* lB1 = &Bld[(wv*2+1)*512];
  int nr0 = n0 + arow0; if(nr0 > N-1) nr0 = N-1;
  int nr1 = n0 + arow1; if(nr1 > N-1) nr1 = N-1;
  int b0=0,y0=0,x0=0,b1=0,y1=0,x1=0;
  if constexpr (CONVC != 0){
    int m_ = m0 + arow0; b0 = m_>>12; int r_ = m_&4095; y0 = r_>>6; x0 = r_&63;
    m_ = m0 + arow1; b1 = m_>>12; r_ = m_&4095; y1 = r_>>6; x1 = r_&63;
  }
  f32x4 acc[4][4];
  #pragma unroll
  for(int i=0;i<4;i++)
    #pragma unroll
    for(int j=0;j<4;j++) acc[i][j] = (f32x4){0.f,0.f,0.f,0.f};
  const int nIter = Kd >> 5;
  for(int kt=0; kt<nIter; ++kt){
    const int k0x = kt*32;
    const u16 *ga0, *ga1;
    if constexpr (CONVC != 0){
      const int tap = k0x / CONVC;
      const int ic0 = k0x - tap*CONVC;
      const int ky = tap/3, kx = tap - 3*(tap/3);
      ga0 = A + ((size_t)((b0*66 + y0+ky)*66 + (x0+kx)))*CONVC + ic0 + acol;
      ga1 = A + ((size_t)((b1*66 + y1+ky)*66 + (x1+kx)))*CONVC + ic0 + acol;
    } else {
      ga0 = A + (size_t)(m0+arow0)*Kd + k0x + acol;
      ga1 = A + (size_t)(m0+arow1)*Kd + k0x + acol;
    }
    gload16(ga0, lA0); gload16(ga1, lA1);
    gload16(Wt + (size_t)nr0*Kd + k0x + acol, lB0);
    gload16(Wt + (size_t)nr1*Kd + k0x + acol, lB1);
    __syncthreads();
    short8 af[4], bfr[4];
    #pragma unroll
    for(int i=0;i<4;i++){
      af[i]  = *(const short8*)&Ald[(wm + i*16 + lr)*32 + g*8];
      bfr[i] = *(const short8*)&Bld[(wn + i*16 + lr)*32 + g*8];
    }
    #pragma unroll
    for(int i=0;i<4;i++)
      #pragma unroll
      for(int j=0;j<4;j++)
        acc[i][j] = mfma16(af[i], bfr[j], acc[i][j]);
    __syncthreads();
  }
  #pragma unroll
  for(int i=0;i<4;i++){
    #pragma unroll
    for(int j=0;j<4;j++){
      #pragma unroll
      for(int r=0;r<4;r++){
        const int mrow = m0 + wm + i*16 + g*4 + r;
        const int ncol = n0 + wn + j*16 + lr;
        float val = acc[i][j][r];
        if constexpr (EPI==0 || EPI==3 || EPI==4 || EPI==5 || EPI==6)
          val += bias[ncol < N ? ncol : N-1];
        if constexpr (EPI==0){
          ((float*)outp)[(size_t)mrow*512 + ncol] = val;
        } else if constexpr (EPI==1){
          const int sec = ncol >> 9, rem = ncol & 511;
          const int head = rem >> 6, d = rem & 63;
          const int b = mrow >> 10, t = mrow & 1023;
          ((u16*)outp)[(size_t)sec*4194304 + ((size_t)((b*8+head)*1024 + t))*64 + d] = f2bf(val);
        } else if constexpr (EPI==2 || EPI==4){
          const size_t idx = (size_t)mrow*512 + ncol;
          ((float*)outp)[idx] = resid[idx] + val;
        } else if constexpr (EPI==3){
          const float gl = 0.5f * val * (1.f + erff(val * 0.70710678118654752f));
          ((u16*)outp)[(size_t)mrow*512 + ncol] = f2bf(gl);
        } else if constexpr (EPI==5){
          const int b = mrow>>12; const int rr = mrow&4095; const int y = rr>>6; const int xx = rr&63;
          const size_t pidx = ((size_t)(b*1024 + (y>>1)*32 + (xx>>1)))*512 + (y&1)*256 + (xx&1)*128 + ncol;
          ((float*)outp)[pidx] = val;
        } else if constexpr (EPI==6){
          if(ncol < N){
            const int b = mrow>>12; const int rr = mrow&4095; const int y = rr>>6; const int xx = rr&63;
            ((float*)outp)[(((size_t)(b*320 + ncol))*64 + y)*64 + xx] = val;
          }
        }
      }
    }
  }
}

// ---------------- attention pass A: global min of scaled dots ----------------
__global__ __launch_bounds__(256)
void k_attn_min(const u16* __restrict__ q, const u16* __restrict__ k, u32* __restrict__ minbuf, int layer){
  const int qt = blockIdx.x, bh = blockIdx.y;
  __shared__ u16 Kld[32*64];
  __shared__ float red[4];
  const int tid = threadIdx.x, lane = tid & 63, wv = tid >> 6;
  const int lr = lane & 15, g = lane >> 4;
  const u16* qp = q + ((size_t)bh*1024 + qt*64 + wv*16 + lr)*64;
  const short8 qa0 = *(const short8*)(qp + g*8);
  const short8 qa1 = *(const short8*)(qp + 32 + g*8);
  float mn = 3.0e38f;
  for(int jt=0; jt<32; ++jt){
    __syncthreads();
    { const int row = tid>>3, cq = tid&7;
      *(short8*)&Kld[row*64 + ((cq ^ (row&7))<<3)] =
        *(const short8*)(k + ((size_t)bh*1024 + jt*32 + row)*64 + cq*8);
    }
    __syncthreads();
    #pragma unroll
    for(int c=0;c<2;c++){
      const int rr = c*16 + lr;
      const short8 kb0 = *(const short8*)&Kld[rr*64 + ((g ^ (lr&7))<<3)];
      const short8 kb1 = *(const short8*)&Kld[rr*64 + (((g+4) ^ (lr&7))<<3)];
      f32x4 sacc = (f32x4){0.f,0.f,0.f,0.f};
      sacc = mfma16(qa0, kb0, sacc);
      sacc = mfma16(qa1, kb1, sacc);
      #pragma unroll
      for(int r=0;r<4;r++) mn = fminf(mn, sacc[r]);
    }
  }
  mn *= 0.125f;
  #pragma unroll
  for(int off=32; off; off>>=1) mn = fminf(mn, __shfl_down(mn, off));
  if(lane==0) red[wv] = mn;
  __syncthreads();
  if(tid==0){
    const float m2 = fminf(fminf(red[0],red[1]), fminf(red[2],red[3]));
    atomicMin(minbuf + layer, fkey(m2));
  }
}

// ---------------- attention pass B: flash with mask + min_val ----------------
__global__ __launch_bounds__(256)
void k_attn(const u16* __restrict__ q, const u16* __restrict__ k, const u16* __restrict__ v,
            const unsigned char* __restrict__ rm, const u32* __restrict__ minbuf,
            u16* __restrict__ o, int layer){
  const int qt = blockIdx.x, bh = blockIdx.y; const int b = bh>>3, h = bh&7;
  __shared__ u16 Kld[32*64];
  __shared__ u16 Vt[64*32];
  __shared__ u16 Pld[4][16*32];
  const int tid = threadIdx.x, lane = tid & 63, wv = tid >> 6;
  const int lr = lane & 15, g = lane >> 4;
  const u16* qp = q + ((size_t)bh*1024 + qt*64 + wv*16 + lr)*64;
  const short8 qa0 = *(const short8*)(qp + g*8);
  const short8 qa1 = *(const short8*)(qp + 32 + g*8);
  const float minv = funkey(minbuf[layer]);
  const unsigned char* rmp = rm + (size_t)(layer*8 + b)*1024;
  bool rroww[4];
  #pragma unroll
  for(int r=0;r<4;r++) rroww[r] = rmp[qt*64 + wv*16 + g*4 + r] != 0;
  float mrun[4], lrun[4];
  #pragma unroll
  for(int r=0;r<4;r++){ mrun[r] = -3.0e38f; lrun[r] = 0.f; }
  f32x4 accd[4];
  #pragma unroll
  for(int d=0;d<4;d++) accd[d] = (f32x4){0.f,0.f,0.f,0.f};

  for(int jt=0; jt<32; ++jt){
    const int j0 = jt*32;
    __syncthreads();
    { const int row = tid>>3, cq = tid&7;
      *(short8*)&Kld[row*64 + ((cq ^ (row&7))<<3)] =
        *(const short8*)(k + ((size_t)bh*1024 + j0 + row)*64 + cq*8);
      const short8 vv = *(const short8*)(v + ((size_t)bh*1024 + j0 + row)*64 + cq*8);
      #pragma unroll
      for(int i=0;i<8;i++){
        const int d_ = cq*8 + i;
        Vt[d_*32 + (row ^ ((d_&3)<<3))] = (u16)vv[i];
      }
    }
    __syncthreads();
    float p[2][4];
    #pragma unroll
    for(int c=0;c<2;c++){
      const int rr = c*16 + lr;
      const short8 kb0 = *(const short8*)&Kld[rr*64 + ((g ^ (lr&7))<<3)];
      const short8 kb1 = *(const short8*)&Kld[rr*64 + (((g+4) ^ (lr&7))<<3)];
      f32x4 sacc = (f32x4){0.f,0.f,0.f,0.f};
      sacc = mfma16(qa0, kb0, sacc);
      sacc = mfma16(qa1, kb1, sacc);
      const bool colok = rmp[j0 + c*16 + lr] != 0;
      #pragma unroll
      for(int r=0;r<4;r++){
        float vl = sacc[r]*0.125f;
        if(!(rroww[r] || colok)) vl = minv;
        p[c][r] = vl;
      }
    }
    float sf[4];
    #pragma unroll
    for(int r=0;r<4;r++){
      float mx = fmaxf(p[0][r], p[1][r]);
      mx = fmaxf(mx, __shfl_xor(mx,1)); mx = fmaxf(mx, __shfl_xor(mx,2));
      mx = fmaxf(mx, __shfl_xor(mx,4)); mx = fmaxf(mx, __shfl_xor(mx,8));
      const float mnew = fmaxf(mrun[r], mx);
      const float e0 = expf(p[0][r] - mnew);
      const float e1 = expf(p[1][r] - mnew);
      p[0][r] = e0; p[1][r] = e1;
      float ts = e0 + e1;
      ts += __shfl_xor(ts,1); ts += __shfl_xor(ts,2); ts += __shfl_xor(ts,4); ts += __shfl_xor(ts,8);
      sf[r] = expf(mrun[r] - mnew);
      lrun[r] = lrun[r]*sf[r] + ts;
      mrun[r] = mnew;
    }
    #pragma unroll
    for(int d=0;d<4;d++)
      #pragma unroll
      for(int r=0;r<4;r++) accd[d][r] *= sf[r];
    // P -> LDS (swizzled), row = g*4+r, col = c*16+lr
    #pragma unroll
    for(int c=0;c<2;c++)
      #pragma unroll
      for(int r=0;r<4;r++){
        const int ql = g*4+r, cl = c*16+lr;
        Pld[wv][ql*32 + (cl ^ ((ql&3)<<3))] = f2bf(p[c][r]);
      }
    const short8 pa = *(const short8*)&Pld[wv][lr*32 + ((g ^ (lr&3))<<3)];
    #pragma unroll
    for(int d=0;d<4;d++){
      const short8 vb = *(const short8*)&Vt[(d*16+lr)*32 + ((g ^ (lr&3))<<3)];
      accd[d] = mfma16(pa, vb, accd[d]);
    }
  }
  #pragma unroll
  for(int d=0;d<4;d++)
    #pragma unroll
    for(int r=0;r<4;r++){
      const int qrow = qt*64 + wv*16 + g*4 + r;
      o[((size_t)b*1024 + qrow)*512 + h*64 + d*16 + lr] = f2bf(accd[d][r] / lrun[r]);
    }
}

// ---------------- host ----------------
extern "C" void kernel_launch(void* const* d_in, const int* in_sizes, int n_in,
                              void* d_out, int out_size, void* d_ws, size_t ws_size,
                              hipStream_t stream)
{
  const float* img     = (const float*)d_in[0];
  const int*   mask    = (const int*)d_in[1];
  const float* conv1_w = (const float*)d_in[2];
  const float* conv1_b = (const float*)d_in[3];
  const float* ln_p_g  = (const float*)d_in[4];
  const float* ln_p_b  = (const float*)d_in[5];
  const float* proj_w  = (const float*)d_in[6];
  const float* proj_b  = (const float*)d_in[7];
  const float* ln_q_g  = (const float*)d_in[8];
  const float* ln_q_b  = (const float*)d_in[9];
  const float* attn_ln_g = (const float*)d_in[10];
  const float* attn_ln_b = (const float*)d_in[11];
  const float* wqkv    = (const float*)d_in[12];
  const float* wo      = (const float*)d_in[13];
  const float* ff_ln_g = (const float*)d_in[14];
  const float* ff_ln_b = (const float*)d_in[15];
  const float* w1      = (const float*)d_in[16];
  const float* b1      = (const float*)d_in[17];
  const float* w2      = (const float*)d_in[18];
  const float* b2      = (const float*)d_in[19];
  const float* conv2_w = (const float*)d_in[20];
  const float* conv2_b = (const float*)d_in[21];

  if(ws_size < WS_NEED) return;
  char* ws = (char*)d_ws;
  u16* projWt = (u16*)(ws + O_PROJW);
  u16* qkvWt  = (u16*)(ws + O_QKVW);
  u16* woWt   = (u16*)(ws + O_WOW);
  u16* w1Wt   = (u16*)(ws + O_W1W);
  u16* w2Wt   = (u16*)(ws + O_W2W);
  u16* c1Wt   = (u16*)(ws + O_C1W);
  u16* c2Wt   = (u16*)(ws + O_C2W);
  u16* pcl    = (u16*)(ws + O_RA);      // pcl1 then pcl2
  float* tmpf = (float*)(ws + O_RA);    // proj out (after pcl1 dead)
  float* patches = (float*)(ws + O_RB);
  u16* qkvb   = (u16*)(ws + O_RB);      // q|k|v, each 8*8*1024*64
  float* xbuf = (float*)(ws + O_X);
  u16* xnbf   = (u16*)(ws + O_D);
  u16* obf    = (u16*)(ws + O_F);
  unsigned char* rmb = (unsigned char*)(ws + O_RM);
  u32* minbuf = (u32*)(ws + O_MIN);

  hipMemsetAsync(ws + O_MIN, 0xFF, 64, stream);
  hipMemsetAsync(ws + O_RA, 0, 22302720, stream);   // pcl1 zero borders

  // weight conversion
  k_transpose_bf<<<dim3(16,16,1),256,0,stream>>>(proj_w, projWt, 512, 512);
  k_transpose_bf<<<dim3(16,48,6),256,0,stream>>>(wqkv,   qkvWt,  512, 1536);
  k_transpose_bf<<<dim3(16,16,6),256,0,stream>>>(wo,     woWt,   512, 512);
  k_transpose_bf<<<dim3(16,16,6),256,0,stream>>>(w1,     w1Wt,   512, 512);
  k_transpose_bf<<<dim3(16,16,6),256,0,stream>>>(w2,     w2Wt,   512, 512);
  k_convw<<<1440,256,0,stream>>>(conv1_w, c1Wt, 128, 320);
  k_convw<<<1440,256,0,stream>>>(conv2_w, c2Wt, 320, 128);
  k_rmask<<<192,256,0,stream>>>(mask, rmb);

  // patch embed
  k_pad_img<<<dim3(512,5),256,0,stream>>>(img, pcl);
  k_gemm<5,320><<<dim3(256,1),256,0,stream>>>(pcl, c1Wt, conv1_b, patches, nullptr, 32768, 128, 2880);
  k_ln_bf<<<8192,256,0,stream>>>(patches, ln_p_g, ln_p_b, xnbf);
  k_gemm<0,0><<<dim3(64,4),256,0,stream>>>(xnbf, projWt, proj_b, tmpf, nullptr, 8192, 512, 512);
  k_lnq_pos<<<8192,256,0,stream>>>(tmpf, ln_q_g, ln_q_b, xbuf);

  const u16* qb = qkvb;
  const u16* kb = qkvb + 4194304;
  const u16* vb = qkvb + 8388608;
  for(int i=0;i<6;i++){
    k_ln_bf<<<8192,256,0,stream>>>(xbuf, attn_ln_g + i*512, attn_ln_b + i*512, xnbf);
    k_gemm<1,0><<<dim3(64,12),256,0,stream>>>(xnbf, qkvWt + (size_t)i*1536*512, nullptr, qkvb, nullptr, 8192, 1536, 512);
    k_attn_min<<<dim3(16,64),256,0,stream>>>(qb, kb, minbuf, i);
    k_attn<<<dim3(16,64),256,0,stream>>>(qb, kb, vb, rmb, minbuf, obf, i);
    k_gemm<2,0><<<dim3(64,4),256,0,stream>>>(obf, woWt + (size_t)i*512*512, nullptr, xbuf, xbuf, 8192, 512, 512);
    k_ln_bf<<<8192,256,0,stream>>>(xbuf, ff_ln_g + i*512, ff_ln_b + i*512, xnbf);
    k_gemm<3,0><<<dim3(64,4),256,0,stream>>>(xnbf, w1Wt + (size_t)i*512*512, b1 + i*512, obf, nullptr, 8192, 512, 512);
    k_gemm<4,0><<<dim3(64,4),256,0,stream>>>(obf, w2Wt + (size_t)i*512*512, b2 + i*512, xbuf, xbuf, 8192, 512, 512);
  }

  // final conv
  hipMemsetAsync(ws + O_RA, 0, 8921088, stream);    // pcl2 zero borders
  k_pad_tok<<<16384,256,0,stream>>>(xbuf, pcl);
  k_gemm<6,128><<<dim3(256,3),256,0,stream>>>(pcl, c2Wt, conv2_b, d_out, nullptr, 32768, 320, 1152);
}

// Round 2
// 1291.716 us; speedup vs baseline: 1.2821x; 1.2821x over previous
//
#include <hip/hip_runtime.h>
#include <hip/hip_bf16.h>
#include <math.h>

typedef __attribute__((ext_vector_type(8))) short short8;
typedef __attribute__((ext_vector_type(4))) float f32x4;
typedef unsigned short u16;
typedef unsigned int u32;

#define DEV __device__ __forceinline__

DEV float bf2f(u16 u){ u32 x = ((u32)u)<<16; return __builtin_bit_cast(float, x); }
DEV u16 f2bf(float f){ u32 x = __builtin_bit_cast(u32, f); return (u16)((x + 0x7FFFu + ((x>>16)&1u))>>16); }
DEV f32x4 mfma16(short8 a, short8 b, f32x4 c){ return __builtin_amdgcn_mfma_f32_16x16x32_bf16(a,b,c,0,0,0); }
DEV void gload16(const void* g, void* l){
  __builtin_amdgcn_global_load_lds((const __attribute__((address_space(1))) void*)g,
                                   (__attribute__((address_space(3))) void*)l, 16, 0, 0);
}
DEV u32 fkey(float f){ u32 b = __builtin_bit_cast(u32, f); return (b & 0x80000000u) ? ~b : (b ^ 0x80000000u); }
DEV float funkey(u32 k){ u32 b = (k & 0x80000000u) ? (k ^ 0x80000000u) : ~k; return __builtin_bit_cast(float, b); }

// ---------------- workspace layout (bytes) ----------------
static constexpr size_t O_PROJW = 0;                         // 512*512*2
static constexpr size_t O_QKVW  = O_PROJW + 524288;          // 6*1536*512*2
static constexpr size_t O_WOW   = O_QKVW + 9437184;          // 6*512*512*2
static constexpr size_t O_W1W   = O_WOW + 3145728;
static constexpr size_t O_W2W   = O_W1W + 3145728;
static constexpr size_t O_C1W   = O_W2W + 3145728;           // 128*2880*2
static constexpr size_t O_C2W   = O_C1W + 737280;            // 320*1152*2
static constexpr size_t O_RA    = O_C2W + 737280;            // pcl1 22.3MB / tmp f32 / vt 8.4MB / pcl2
static constexpr size_t O_RB    = O_RA + 22302720;           // patches f32 16.8MB then qkv bf16 25.2MB
static constexpr size_t O_X     = O_RB + 25165824;           // x f32 16.8MB
static constexpr size_t O_D     = O_X + 16777216;            // xn bf16 8.4MB
static constexpr size_t O_F     = O_D + 8388608;             // o/g bf16 8.4MB
static constexpr size_t O_RM    = O_F + 8388608;             // 48*1024 u8
static constexpr size_t O_MIN   = O_RM + 49152;              // 6 u32 keys
static constexpr size_t WS_NEED = O_MIN + 256;

// ---------------- weight conversion ----------------
// src [z][K][N] f32 -> dst [z][N][K] bf16
__global__ __launch_bounds__(256) void k_transpose_bf(const float* __restrict__ src, u16* __restrict__ dst, int K, int N){
  __shared__ float tile[32][33];
  const int k0 = blockIdx.x*32, n0 = blockIdx.y*32;
  src += (size_t)blockIdx.z*K*N; dst += (size_t)blockIdx.z*K*N;
  const int c = threadIdx.x & 31, r4 = threadIdx.x >> 5;
  for(int r=r4; r<32; r+=8) tile[r][c] = src[(size_t)(k0+r)*N + n0+c];
  __syncthreads();
  for(int r=r4; r<32; r+=8) dst[(size_t)(n0+r)*K + k0+c] = f2bf(tile[c][r]);
}

// conv weights [OC][IC][3][3] f32 -> Wt [OC][tap*IC+ic] bf16
__global__ __launch_bounds__(256) void k_convw(const float* __restrict__ src, u16* __restrict__ dst, int OC, int IC){
  int idx = blockIdx.x*256 + threadIdx.x;
  int total = OC*IC*9;
  if(idx >= total) return;
  int oc = idx/(IC*9); int rem = idx - oc*IC*9; int tap = rem/IC; int ic = rem - tap*IC;
  dst[idx] = f2bf(src[(size_t)(oc*IC+ic)*9 + tap]);
}

// img [8][320][64][64] f32 -> pcl1 [8][66][66][320] bf16 (interior; borders pre-zeroed)
__global__ __launch_bounds__(256) void k_pad_img(const float* __restrict__ img, u16* __restrict__ pcl){
  const int by = blockIdx.x; const int b = by>>6, y = by&63; const int c0 = blockIdx.y*64;
  __shared__ float t[64][65];
  const int tx = threadIdx.x & 63, tz = threadIdx.x >> 6;
  for(int ci=tz; ci<64; ci+=4) t[ci][tx] = img[(((size_t)b*320 + c0+ci)*64 + y)*64 + tx];
  __syncthreads();
  for(int x=tz; x<64; x+=4) pcl[(((size_t)b*66 + y+1)*66 + (x+1))*320 + c0 + tx] = f2bf(t[tx][x]);
}

// x tokens f32 -> pcl2 [8][66][66][128] bf16 (interior)
__global__ __launch_bounds__(256) void k_pad_tok(const float* __restrict__ x, u16* __restrict__ pcl){
  int idx = blockIdx.x*256 + threadIdx.x;           // 8*64*64*128
  const int c = idx & 127; int r = idx >> 7; const int xx = r & 63; r >>= 6; const int yy = r & 63; const int b = r >> 6;
  const int n = (yy>>1)*32 + (xx>>1); const int f = (yy&1)*256 + (xx&1)*128 + c;
  pcl[(((size_t)b*66 + yy+1)*66 + xx+1)*128 + c] = f2bf(x[((size_t)b*1024 + n)*512 + f]);
}

// mask [48][64][64] int -> rm [48][1024] u8 (2x2 any)
__global__ __launch_bounds__(256) void k_rmask(const int* __restrict__ mask, unsigned char* __restrict__ rm){
  int idx = blockIdx.x*256 + threadIdx.x;
  if(idx >= 48*1024) return;
  const int m = idx >> 10, n = idx & 1023; const int h = n>>5, w = n&31;
  const int* mp = mask + ((size_t)m*64 + h*2)*64 + w*2;
  rm[idx] = (unsigned char)((mp[0]==1) | (mp[1]==1) | (mp[64]==1) | (mp[65]==1));
}

// v [64 bh][1024 n][64 d] -> vt [64 bh][64 d][1024 n]
__global__ __launch_bounds__(256) void k_vt(const u16* __restrict__ v, u16* __restrict__ vt){
  const int nt = blockIdx.x, bh = blockIdx.y;
  __shared__ u16 t[64][72];
  const int tid = threadIdx.x;
  const int i = tid>>2, cq = tid&3;
  const u16* src = v + ((size_t)bh*1024 + nt*64 + i)*64 + cq*16;
  const short8 s0 = *(const short8*)src;
  const short8 s1 = *(const short8*)(src+8);
  #pragma unroll
  for(int e=0;e<8;e++){ t[cq*16+e][i] = (u16)s0[e]; t[cq*16+8+e][i] = (u16)s1[e]; }
  __syncthreads();
  short8 o0, o1;
  #pragma unroll
  for(int e=0;e<8;e++){ o0[e] = (short)t[i][cq*16+e]; o1[e] = (short)t[i][cq*16+8+e]; }
  u16* dst = vt + (size_t)bh*65536 + (size_t)i*1024 + nt*64 + cq*16;
  *(short8*)dst = o0;
  *(short8*)(dst+8) = o1;
}

// ---------------- layernorm (wave per token) ----------------
__global__ __launch_bounds__(256) void k_ln_bf(const float* __restrict__ in, const float* __restrict__ gw,
                                               const float* __restrict__ bw, u16* __restrict__ out){
  const int tok = blockIdx.x*4 + (threadIdx.x>>6);
  const int lane = threadIdx.x & 63;
  const float* rp = in + (size_t)tok*512 + lane*8;
  const float4 a = *(const float4*)rp;
  const float4 b = *(const float4*)(rp+4);
  float s  = a.x+a.y+a.z+a.w + b.x+b.y+b.z+b.w;
  float sq = a.x*a.x+a.y*a.y+a.z*a.z+a.w*a.w + b.x*b.x+b.y*b.y+b.z*b.z+b.w*b.w;
  #pragma unroll
  for(int off=1; off<64; off<<=1){ s += __shfl_xor(s,off); sq += __shfl_xor(sq,off); }
  const float mu = s*(1.f/512.f);
  const float rs = rsqrtf(sq*(1.f/512.f) - mu*mu + 1e-5f);
  const float4 g0 = *(const float4*)(gw + lane*8);
  const float4 g1 = *(const float4*)(gw + lane*8 + 4);
  const float4 b0 = *(const float4*)(bw + lane*8);
  const float4 b1 = *(const float4*)(bw + lane*8 + 4);
  short8 o8;
  o8[0]=f2bf((a.x-mu)*rs*g0.x+b0.x); o8[1]=f2bf((a.y-mu)*rs*g0.y+b0.y);
  o8[2]=f2bf((a.z-mu)*rs*g0.z+b0.z); o8[3]=f2bf((a.w-mu)*rs*g0.w+b0.w);
  o8[4]=f2bf((b.x-mu)*rs*g1.x+b1.x); o8[5]=f2bf((b.y-mu)*rs*g1.y+b1.y);
  o8[6]=f2bf((b.z-mu)*rs*g1.z+b1.z); o8[7]=f2bf((b.w-mu)*rs*g1.w+b1.w);
  *(short8*)(out + (size_t)tok*512 + lane*8) = o8;
}

// LN + sincos 2d posemb -> f32 x (wave per token)
__global__ __launch_bounds__(256) void k_lnq_pos(const float* __restrict__ in, const float* __restrict__ gw,
                                                 const float* __restrict__ bw, float* __restrict__ out){
  const int tok = blockIdx.x*4 + (threadIdx.x>>6);
  const int lane = threadIdx.x & 63;
  const float* rp = in + (size_t)tok*512 + lane*8;
  const float4 a = *(const float4*)rp;
  const float4 b = *(const float4*)(rp+4);
  float s  = a.x+a.y+a.z+a.w + b.x+b.y+b.z+b.w;
  float sq = a.x*a.x+a.y*a.y+a.z*a.z+a.w*a.w + b.x*b.x+b.y*b.y+b.z*b.z+b.w*b.w;
  #pragma unroll
  for(int off=1; off<64; off<<=1){ s += __shfl_xor(s,off); sq += __shfl_xor(sq,off); }
  const float mu = s*(1.f/512.f);
  const float rs = rsqrtf(sq*(1.f/512.f) - mu*mu + 1e-5f);
  const int n = tok & 1023; const int yy = n>>5, xx = n&31;
  const int f0 = lane*8; const int sec = f0>>7;
  const float coord = (sec<2) ? (float)xx : (float)yy;
  const float vv[8] = {a.x,a.y,a.z,a.w,b.x,b.y,b.z,b.w};
  float ov[8];
  #pragma unroll
  for(int j=0;j<8;j++){
    const int f = f0+j; const int qq = f & 127;
    const float om = __expf(-(float)qq * (9.2103403719761836f/127.f));
    const float arg = coord * om;
    const float pe = (sec&1) ? __cosf(arg) : __sinf(arg);
    ov[j] = (vv[j]-mu)*rs*gw[f] + bw[f] + pe;
  }
  float* op = out + (size_t)tok*512 + f0;
  *(float4*)op = (float4){ov[0],ov[1],ov[2],ov[3]};
  *(float4*)(op+4) = (float4){ov[4],ov[5],ov[6],ov[7]};
}

// ---------------- GEMM (128x128 tile, BK=32, 4 waves, global_load_lds) ----------------
// EPI: 0 proj(f32+bias) 1 qkv-scatter(bf16) 2 resid(f32) 3 gelu(bf16+bias) 4 resid+bias 5 conv1->patches 6 conv2->out
template<int EPI, int CONVC>
__global__ __launch_bounds__(256)
void k_gemm(const u16* __restrict__ A, const u16* __restrict__ Wt,
            const float* __restrict__ bias, void* __restrict__ outp,
            const float* __restrict__ resid, int M, int N, int Kd)
{
  __shared__ u16 Ald[128*32];
  __shared__ u16 Bld[128*32];
  const int tid = threadIdx.x, lane = tid & 63, wv = tid >> 6;
  const int lr = lane & 15, g = lane >> 4;
  const int m0 = blockIdx.x * 128, n0 = blockIdx.y * 128;
  const int wm = (wv >> 1) * 64, wn = (wv & 1) * 64;
  const int arow0 = wv*32 + (lane>>2);
  const int arow1 = arow0 + 16;
  const int acol = (lane & 3) * 8;
  u16* lA0 = &Ald[(wv*2+0)*512]; u16* lA1 = &Ald[(wv*2+1)*512];
  u16* lB0 = &Bld[(wv*2+0)*512]; u16* lB1 = &Bld[(wv*2+1)*512];
  int nr0 = n0 + arow0; if(nr0 > N-1) nr0 = N-1;
  int nr1 = n0 + arow1; if(nr1 > N-1) nr1 = N-1;
  int b0=0,y0=0,x0=0,b1=0,y1=0,x1=0;
  if constexpr (CONVC != 0){
    int m_ = m0 + arow0; b0 = m_>>12; int r_ = m_&4095; y0 = r_>>6; x0 = r_&63;
    m_ = m0 + arow1; b1 = m_>>12; r_ = m_&4095; y1 = r_>>6; x1 = r_&63;
  }
  f32x4 acc[4][4];
  #pragma unroll
  for(int i=0;i<4;i++)
    #pragma unroll
    for(int j=0;j<4;j++) acc[i][j] = (f32x4){0.f,0.f,0.f,0.f};
  const int nIter = Kd >> 5;
  for(int kt=0; kt<nIter; ++kt){
    const int k0x = kt*32;
    const u16 *ga0, *ga1;
    if constexpr (CONVC != 0){
      const int tap = k0x / CONVC;
      const int ic0 = k0x - tap*CONVC;
      const int ky = tap/3, kx = tap - 3*(tap/3);
      ga0 = A + ((size_t)((b0*66 + y0+ky)*66 + (x0+kx)))*CONVC + ic0 + acol;
      ga1 = A + ((size_t)((b1*66 + y1+ky)*66 + (x1+kx)))*CONVC + ic0 + acol;
    } else {
      ga0 = A + (size_t)(m0+arow0)*Kd + k0x + acol;
      ga1 = A + (size_t)(m0+arow1)*Kd + k0x + acol;
    }
    gload16(ga0, lA0); gload16(ga1, lA1);
    gload16(Wt + (size_t)nr0*Kd + k0x + acol, lB0);
    gload16(Wt + (size_t)nr1*Kd + k0x + acol, lB1);
    __syncthreads();
    short8 af[4], bfr[4];
    #pragma unroll
    for(int i=0;i<4;i++){
      af[i]  = *(const short8*)&Ald[(wm + i*16 + lr)*32 + g*8];
      bfr[i] = *(const short8*)&Bld[(wn + i*16 + lr)*32 + g*8];
    }
    #pragma unroll
    for(int i=0;i<4;i++)
      #pragma unroll
      for(int j=0;j<4;j++)
        acc[i][j] = mfma16(af[i], bfr[j], acc[i][j]);
    __syncthreads();
  }
  #pragma unroll
  for(int i=0;i<4;i++){
    #pragma unroll
    for(int j=0;j<4;j++){
      #pragma unroll
      for(int r=0;r<4;r++){
        const int mrow = m0 + wm + i*16 + g*4 + r;
        const int ncol = n0 + wn + j*16 + lr;
        float val = acc[i][j][r];
        if constexpr (EPI==0 || EPI==3 || EPI==4 || EPI==5 || EPI==6)
          val += bias[ncol < N ? ncol : N-1];
        if constexpr (EPI==0){
          ((float*)outp)[(size_t)mrow*512 + ncol] = val;
        } else if constexpr (EPI==1){
          const int sec = ncol >> 9, rem = ncol & 511;
          const int head = rem >> 6, d = rem & 63;
          const int b = mrow >> 10, t = mrow & 1023;
          ((u16*)outp)[(size_t)sec*4194304 + ((size_t)((b*8+head)*1024 + t))*64 + d] = f2bf(val);
        } else if constexpr (EPI==2 || EPI==4){
          const size_t idx = (size_t)mrow*512 + ncol;
          ((float*)outp)[idx] = resid[idx] + val;
        } else if constexpr (EPI==3){
          const float gl = 0.5f * val * (1.f + erff(val * 0.70710678118654752f));
          ((u16*)outp)[(size_t)mrow*512 + ncol] = f2bf(gl);
        } else if constexpr (EPI==5){
          const int b = mrow>>12; const int rr = mrow&4095; const int y = rr>>6; const int xx = rr&63;
          const size_t pidx = ((size_t)(b*1024 + (y>>1)*32 + (xx>>1)))*512 + (y&1)*256 + (xx&1)*128 + ncol;
          ((float*)outp)[pidx] = val;
        } else if constexpr (EPI==6){
          if(ncol < N){
            const int b = mrow>>12; const int rr = mrow&4095; const int y = rr>>6; const int xx = rr&63;
            ((float*)outp)[(((size_t)(b*320 + ncol))*64 + y)*64 + xx] = val;
          }
        }
      }
    }
  }
}

// ---------------- attention pass A: global min of scaled dots ----------------
__global__ __launch_bounds__(256, 4)
void k_attn_min(const u16* __restrict__ q, const u16* __restrict__ k, u32* __restrict__ minbuf, int layer){
  const int qt = blockIdx.x, bh = blockIdx.y;
  __shared__ u16 Kld[2][4096];
  __shared__ float red[4];
  const int tid = threadIdx.x, lane = tid & 63, wv = tid >> 6;
  const int lr = lane & 15, g = lane >> 4;
  const u16* qp = q + ((size_t)bh*1024 + qt*64 + wv*16 + lr)*64;
  const short8 qa0 = *(const short8*)(qp + g*8);
  const short8 qa1 = *(const short8*)(qp + 32 + g*8);
  const u16* kbase = k + (size_t)bh*65536;
  const int srow = ((wv*64 + lane)>>3), scs = lane&7;
  const int scg = scs ^ (srow&7);
  const int srow2 = srow + 32;
  const int scg2 = scs ^ (srow2&7);
  float mn = 3.0e38f;
  // prologue stage jt=0
  gload16(kbase + (size_t)srow*64 + scg*8, &Kld[0][wv*512]);
  gload16(kbase + (size_t)srow2*64 + scg2*8, &Kld[0][2048 + wv*512]);
  int cur = 0;
  for(int jt=0; jt<16; ++jt){
    __syncthreads();
    if(jt < 15){
      const int j1 = (jt+1)*64;
      gload16(kbase + (size_t)(j1+srow)*64 + scg*8, &Kld[cur^1][wv*512]);
      gload16(kbase + (size_t)(j1+srow2)*64 + scg2*8, &Kld[cur^1][2048 + wv*512]);
    }
    #pragma unroll
    for(int c=0;c<4;c++){
      const int rr = c*16 + lr;
      const short8 kb0 = *(const short8*)&Kld[cur][rr*64 + ((g ^ (rr&7))<<3)];
      const short8 kb1 = *(const short8*)&Kld[cur][rr*64 + (((g+4) ^ (rr&7))<<3)];
      f32x4 s4 = (f32x4){0.f,0.f,0.f,0.f};
      s4 = mfma16(qa0, kb0, s4);
      s4 = mfma16(qa1, kb1, s4);
      mn = fminf(mn, fminf(fminf(s4[0],s4[1]), fminf(s4[2],s4[3])));
    }
    cur ^= 1;
  }
  mn *= 0.125f;
  #pragma unroll
  for(int off=32; off; off>>=1) mn = fminf(mn, __shfl_down(mn, off));
  if(lane==0) red[wv] = mn;
  __syncthreads();
  if(tid==0){
    const float m2 = fminf(fminf(red[0],red[1]), fminf(red[2],red[3]));
    atomicMin(minbuf + layer, fkey(m2));
  }
}

// ---------------- attention pass B: flash with mask + min_val ----------------
__global__ __launch_bounds__(256, 4)
void k_attn(const u16* __restrict__ q, const u16* __restrict__ k, const u16* __restrict__ vt,
            const unsigned char* __restrict__ rm, const u32* __restrict__ minbuf,
            u16* __restrict__ o, int layer){
  const int qt = blockIdx.x, bh = blockIdx.y; const int b = bh>>3, h = bh&7;
  __shared__ u16 Kld[2][4096];
  __shared__ u16 Vtld[2][4096];
  __shared__ u16 Pld[4][1024];
  const int tid = threadIdx.x, lane = tid & 63, wv = tid >> 6;
  const int lr = lane & 15, g = lane >> 4;
  const u16* qp = q + ((size_t)bh*1024 + qt*64 + wv*16 + lr)*64;
  const short8 qa0 = *(const short8*)(qp + g*8);
  const short8 qa1 = *(const short8*)(qp + 32 + g*8);
  const float SC = 0.125f * 1.44269504088896f;           // scale * log2(e)
  const float minv = funkey(minbuf[layer]) * 1.44269504088896f;
  const unsigned char* rmp = rm + (size_t)(layer*8 + b)*1024;
  bool rrow[4];
  #pragma unroll
  for(int r=0;r<4;r++) rrow[r] = rmp[qt*64 + wv*16 + g*4 + r] != 0;
  float mrun[4], lrun[4];
  #pragma unroll
  for(int r=0;r<4;r++){ mrun[r] = -3.0e38f; lrun[r] = 0.f; }
  f32x4 accd[4];
  #pragma unroll
  for(int d=0;d<4;d++) accd[d] = (f32x4){0.f,0.f,0.f,0.f};
  const u16* kbase = k + (size_t)bh*65536;
  const u16* vtbase = vt + (size_t)bh*65536;
  const int srow = ((wv*64 + lane)>>3), scs = lane&7;
  const int scg = scs ^ (srow&7);
  const int srow2 = srow + 32;
  const int scg2 = scs ^ (srow2&7);
  // prologue: stage jt=0
  gload16(kbase + (size_t)srow*64 + scg*8, &Kld[0][wv*512]);
  gload16(kbase + (size_t)srow2*64 + scg2*8, &Kld[0][2048 + wv*512]);
  gload16(vtbase + (size_t)srow*1024 + scg*8, &Vtld[0][wv*512]);
  gload16(vtbase + (size_t)srow2*1024 + scg2*8, &Vtld[0][2048 + wv*512]);
  int cur = 0;
  for(int jt=0; jt<16; ++jt){
    const int j0 = jt*64;
    __syncthreads();                       // staging for cur complete
    if(jt < 15){
      const int j1 = j0 + 64;
      gload16(kbase + (size_t)(j1+srow)*64 + scg*8, &Kld[cur^1][wv*512]);
      gload16(kbase + (size_t)(j1+srow2)*64 + scg2*8, &Kld[cur^1][2048 + wv*512]);
      gload16(vtbase + (size_t)srow*1024 + j1 + scg*8, &Vtld[cur^1][wv*512]);
      gload16(vtbase + (size_t)srow2*1024 + j1 + scg2*8, &Vtld[cur^1][2048 + wv*512]);
    }
    // QK^T (scores in exp2 domain)
    float p4[4][4];
    #pragma unroll
    for(int c=0;c<4;c++){
      const int rr = c*16 + lr;
      const short8 kb0 = *(const short8*)&Kld[cur][rr*64 + ((g ^ (rr&7))<<3)];
      const short8 kb1 = *(const short8*)&Kld[cur][rr*64 + (((g+4) ^ (rr&7))<<3)];
      f32x4 s4 = (f32x4){0.f,0.f,0.f,0.f};
      s4 = mfma16(qa0, kb0, s4);
      s4 = mfma16(qa1, kb1, s4);
      const bool colok = rmp[j0 + rr] != 0;
      #pragma unroll
      for(int r=0;r<4;r++){
        float vl = s4[r]*SC;
        if(!(rrow[r] || colok)) vl = minv;
        p4[c][r] = vl;
      }
    }
    // online softmax (exp2 domain)
    float sf[4];
    #pragma unroll
    for(int r=0;r<4;r++){
      float mx = fmaxf(fmaxf(p4[0][r],p4[1][r]), fmaxf(p4[2][r],p4[3][r]));
      mx = fmaxf(mx, __shfl_xor(mx,1)); mx = fmaxf(mx, __shfl_xor(mx,2));
      mx = fmaxf(mx, __shfl_xor(mx,4)); mx = fmaxf(mx, __shfl_xor(mx,8));
      const float mnew = fmaxf(mrun[r], mx);
      float ts = 0.f;
      #pragma unroll
      for(int c=0;c<4;c++){ const float e = exp2f(p4[c][r]-mnew); p4[c][r] = e; ts += e; }
      ts += __shfl_xor(ts,1); ts += __shfl_xor(ts,2); ts += __shfl_xor(ts,4); ts += __shfl_xor(ts,8);
      sf[r] = exp2f(mrun[r] - mnew);
      lrun[r] = lrun[r]*sf[r] + ts;
      mrun[r] = mnew;
    }
    #pragma unroll
    for(int d=0;d<4;d++)
      #pragma unroll
      for(int r=0;r<4;r++) accd[d][r] *= sf[r];
    // P -> LDS (per-wave, chunk-swizzled)
    #pragma unroll
    for(int c=0;c<4;c++)
      #pragma unroll
      for(int r=0;r<4;r++){
        const int ql = g*4+r, cl = c*16+lr;
        Pld[wv][ql*64 + ((((cl>>3) ^ (ql&7))<<3) | (cl&7))] = f2bf(p4[c][r]);
      }
    const short8 pa0 = *(const short8*)&Pld[wv][lr*64 + ((g ^ (lr&7))<<3)];
    const short8 pa1 = *(const short8*)&Pld[wv][lr*64 + (((g+4) ^ (lr&7))<<3)];
    // PV
    #pragma unroll
    for(int d=0;d<4;d++){
      const int rr = d*16 + lr;
      const short8 vb0 = *(const short8*)&Vtld[cur][rr*64 + ((g ^ (rr&7))<<3)];
      const short8 vb1 = *(const short8*)&Vtld[cur][rr*64 + (((g+4) ^ (rr&7))<<3)];
      accd[d] = mfma16(pa0, vb0, accd[d]);
      accd[d] = mfma16(pa1, vb1, accd[d]);
    }
    cur ^= 1;
  }
  #pragma unroll
  for(int d=0;d<4;d++)
    #pragma unroll
    for(int r=0;r<4;r++){
      const int qrow = qt*64 + wv*16 + g*4 + r;
      o[((size_t)b*1024 + qrow)*512 + h*64 + d*16 + lr] = f2bf(accd[d][r] / lrun[r]);
    }
}

// ---------------- host ----------------
extern "C" void kernel_launch(void* const* d_in, const int* in_sizes, int n_in,
                              void* d_out, int out_size, void* d_ws, size_t ws_size,
                              hipStream_t stream)
{
  const float* img     = (const float*)d_in[0];
  const int*   mask    = (const int*)d_in[1];
  const float* conv1_w = (const float*)d_in[2];
  const float* conv1_b = (const float*)d_in[3];
  const float* ln_p_g  = (const float*)d_in[4];
  const float* ln_p_b  = (const float*)d_in[5];
  const float* proj_w  = (const float*)d_in[6];
  const float* proj_b  = (const float*)d_in[7];
  const float* ln_q_g  = (const float*)d_in[8];
  const float* ln_q_b  = (const float*)d_in[9];
  const float* attn_ln_g = (const float*)d_in[10];
  const float* attn_ln_b = (const float*)d_in[11];
  const float* wqkv    = (const float*)d_in[12];
  const float* wo      = (const float*)d_in[13];
  const float* ff_ln_g = (const float*)d_in[14];
  const float* ff_ln_b = (const float*)d_in[15];
  const float* w1      = (const float*)d_in[16];
  const float* b1      = (const float*)d_in[17];
  const float* w2      = (const float*)d_in[18];
  const float* b2      = (const float*)d_in[19];
  const float* conv2_w = (const float*)d_in[20];
  const float* conv2_b = (const float*)d_in[21];

  if(ws_size < WS_NEED) return;
  char* ws = (char*)d_ws;
  u16* projWt = (u16*)(ws + O_PROJW);
  u16* qkvWt  = (u16*)(ws + O_QKVW);
  u16* woWt   = (u16*)(ws + O_WOW);
  u16* w1Wt   = (u16*)(ws + O_W1W);
  u16* w2Wt   = (u16*)(ws + O_W2W);
  u16* c1Wt   = (u16*)(ws + O_C1W);
  u16* c2Wt   = (u16*)(ws + O_C2W);
  u16* pcl    = (u16*)(ws + O_RA);      // pcl1 / vt / pcl2
  float* tmpf = (float*)(ws + O_RA);    // proj out (after pcl1 dead)
  u16* vtb    = (u16*)(ws + O_RA);      // v^T during layer loop
  float* patches = (float*)(ws + O_RB);
  u16* qkvb   = (u16*)(ws + O_RB);      // q|k|v, each 8*8*1024*64
  float* xbuf = (float*)(ws + O_X);
  u16* xnbf   = (u16*)(ws + O_D);
  u16* obf    = (u16*)(ws + O_F);
  unsigned char* rmb = (unsigned char*)(ws + O_RM);
  u32* minbuf = (u32*)(ws + O_MIN);

  hipMemsetAsync(ws + O_MIN, 0xFF, 64, stream);
  hipMemsetAsync(ws + O_RA, 0, 22302720, stream);   // pcl1 zero borders

  // weight conversion
  k_transpose_bf<<<dim3(16,16,1),256,0,stream>>>(proj_w, projWt, 512, 512);
  k_transpose_bf<<<dim3(16,48,6),256,0,stream>>>(wqkv,   qkvWt,  512, 1536);
  k_transpose_bf<<<dim3(16,16,6),256,0,stream>>>(wo,     woWt,   512, 512);
  k_transpose_bf<<<dim3(16,16,6),256,0,stream>>>(w1,     w1Wt,   512, 512);
  k_transpose_bf<<<dim3(16,16,6),256,0,stream>>>(w2,     w2Wt,   512, 512);
  k_convw<<<1440,256,0,stream>>>(conv1_w, c1Wt, 128, 320);
  k_convw<<<1440,256,0,stream>>>(conv2_w, c2Wt, 320, 128);
  k_rmask<<<192,256,0,stream>>>(mask, rmb);

  // patch embed
  k_pad_img<<<dim3(512,5),256,0,stream>>>(img, pcl);
  k_gemm<5,320><<<dim3(256,1),256,0,stream>>>(pcl, c1Wt, conv1_b, patches, nullptr, 32768, 128, 2880);
  k_ln_bf<<<2048,256,0,stream>>>(patches, ln_p_g, ln_p_b, xnbf);
  k_gemm<0,0><<<dim3(64,4),256,0,stream>>>(xnbf, projWt, proj_b, tmpf, nullptr, 8192, 512, 512);
  k_lnq_pos<<<2048,256,0,stream>>>(tmpf, ln_q_g, ln_q_b, xbuf);

  const u16* qb = qkvb;
  const u16* kb = qkvb + 4194304;
  const u16* vb = qkvb + 8388608;
  for(int i=0;i<6;i++){
    k_ln_bf<<<2048,256,0,stream>>>(xbuf, attn_ln_g + i*512, attn_ln_b + i*512, xnbf);
    k_gemm<1,0><<<dim3(64,12),256,0,stream>>>(xnbf, qkvWt + (size_t)i*1536*512, nullptr, qkvb, nullptr, 8192, 1536, 512);
    k_vt<<<dim3(16,64),256,0,stream>>>(vb, vtb);
    k_attn_min<<<dim3(16,64),256,0,stream>>>(qb, kb, minbuf, i);
    k_attn<<<dim3(16,64),256,0,stream>>>(qb, kb, vtb, rmb, minbuf, obf, i);
    k_gemm<2,0><<<dim3(64,4),256,0,stream>>>(obf, woWt + (size_t)i*512*512, nullptr, xbuf, xbuf, 8192, 512, 512);
    k_ln_bf<<<2048,256,0,stream>>>(xbuf, ff_ln_g + i*512, ff_ln_b + i*512, xnbf);
    k_gemm<3,0><<<dim3(64,4),256,0,stream>>>(xnbf, w1Wt + (size_t)i*512*512, b1 + i*512, obf, nullptr, 8192, 512, 512);
    k_gemm<4,0><<<dim3(64,4),256,0,stream>>>(obf, w2Wt + (size_t)i*512*512, b2 + i*512, xbuf, xbuf, 8192, 512, 512);
  }

  // final conv
  hipMemsetAsync(ws + O_RA, 0, 8921088, stream);    // pcl2 zero borders
  k_pad_tok<<<16384,256,0,stream>>>(xbuf, pcl);
  k_gemm<6,128><<<dim3(256,3),256,0,stream>>>(pcl, c2Wt, conv2_b, d_out, nullptr, 32768, 320, 1152);
}

// Round 3
// 1128.033 us; speedup vs baseline: 1.4681x; 1.1451x over previous
//
#include <hip/hip_runtime.h>
#include <hip/hip_bf16.h>
#include <math.h>

typedef __attribute__((ext_vector_type(8))) short short8;
typedef __attribute__((ext_vector_type(4))) float f32x4;
typedef unsigned short u16;
typedef unsigned int u32;

#define DEV __device__ __forceinline__

DEV float bf2f(u16 u){ u32 x = ((u32)u)<<16; return __builtin_bit_cast(float, x); }
DEV u16 f2bf(float f){ u32 x = __builtin_bit_cast(u32, f); return (u16)((x + 0x7FFFu + ((x>>16)&1u))>>16); }
DEV f32x4 mfma16(short8 a, short8 b, f32x4 c){ return __builtin_amdgcn_mfma_f32_16x16x32_bf16(a,b,c,0,0,0); }
DEV void gload16(const void* g, void* l){
  __builtin_amdgcn_global_load_lds((const __attribute__((address_space(1))) void*)g,
                                   (__attribute__((address_space(3))) void*)l, 16, 0, 0);
}
DEV u32 fkey(float f){ u32 b = __builtin_bit_cast(u32, f); return (b & 0x80000000u) ? ~b : (b ^ 0x80000000u); }
DEV float funkey(u32 k){ u32 b = (k & 0x80000000u) ? (k ^ 0x80000000u) : ~k; return __builtin_bit_cast(float, b); }

// ---------------- workspace layout (bytes) ----------------
static constexpr size_t O_PROJW = 0;                         // 512*512*2
static constexpr size_t O_QKVW  = O_PROJW + 524288;          // 6*1536*512*2
static constexpr size_t O_WOW   = O_QKVW + 9437184;          // 6*512*512*2
static constexpr size_t O_W1W   = O_WOW + 3145728;
static constexpr size_t O_W2W   = O_W1W + 3145728;
static constexpr size_t O_C1W   = O_W2W + 3145728;           // 128*2880*2
static constexpr size_t O_C2W   = O_C1W + 737280;            // 320*1152*2
static constexpr size_t O_RA    = O_C2W + 737280;            // pcl1 22.3MB / tmp f32 / vt 8.4MB / pcl2
static constexpr size_t O_RB    = O_RA + 22302720;           // patches f32 16.8MB then qkv bf16 25.2MB
static constexpr size_t O_X     = O_RB + 25165824;           // x f32 16.8MB
static constexpr size_t O_D     = O_X + 16777216;            // xn bf16 8.4MB
static constexpr size_t O_F     = O_D + 8388608;             // o/g bf16 8.4MB
static constexpr size_t O_RM    = O_F + 8388608;             // 48*1024 u8
static constexpr size_t O_MIN   = O_RM + 49152;              // 6 u32 keys
static constexpr size_t WS_NEED = O_MIN + 256;

// ---------------- weight conversion ----------------
// src [z][K][N] f32 -> dst [z][N][K] bf16
__global__ __launch_bounds__(256) void k_transpose_bf(const float* __restrict__ src, u16* __restrict__ dst, int K, int N){
  __shared__ float tile[32][33];
  const int k0 = blockIdx.x*32, n0 = blockIdx.y*32;
  src += (size_t)blockIdx.z*K*N; dst += (size_t)blockIdx.z*K*N;
  const int c = threadIdx.x & 31, r4 = threadIdx.x >> 5;
  for(int r=r4; r<32; r+=8) tile[r][c] = src[(size_t)(k0+r)*N + n0+c];
  __syncthreads();
  for(int r=r4; r<32; r+=8) dst[(size_t)(n0+r)*K + k0+c] = f2bf(tile[c][r]);
}

// conv weights [OC][IC][3][3] f32 -> Wt [OC][tap*IC+ic] bf16
__global__ __launch_bounds__(256) void k_convw(const float* __restrict__ src, u16* __restrict__ dst, int OC, int IC){
  int idx = blockIdx.x*256 + threadIdx.x;
  int total = OC*IC*9;
  if(idx >= total) return;
  int oc = idx/(IC*9); int rem = idx - oc*IC*9; int tap = rem/IC; int ic = rem - tap*IC;
  dst[idx] = f2bf(src[(size_t)(oc*IC+ic)*9 + tap]);
}

// img [8][320][64][64] f32 -> pcl1 [8][66][66][320] bf16 (interior; borders pre-zeroed)
__global__ __launch_bounds__(256) void k_pad_img(const float* __restrict__ img, u16* __restrict__ pcl){
  const int by = blockIdx.x; const int b = by>>6, y = by&63; const int c0 = blockIdx.y*64;
  __shared__ float t[64][65];
  const int tx = threadIdx.x & 63, tz = threadIdx.x >> 6;
  for(int ci=tz; ci<64; ci+=4) t[ci][tx] = img[(((size_t)b*320 + c0+ci)*64 + y)*64 + tx];
  __syncthreads();
  for(int x=tz; x<64; x+=4) pcl[(((size_t)b*66 + y+1)*66 + (x+1))*320 + c0 + tx] = f2bf(t[tx][x]);
}

// x tokens f32 -> pcl2 [8][66][66][128] bf16 (interior)
__global__ __launch_bounds__(256) void k_pad_tok(const float* __restrict__ x, u16* __restrict__ pcl){
  int idx = blockIdx.x*256 + threadIdx.x;           // 8*64*64*128
  const int c = idx & 127; int r = idx >> 7; const int xx = r & 63; r >>= 6; const int yy = r & 63; const int b = r >> 6;
  const int n = (yy>>1)*32 + (xx>>1); const int f = (yy&1)*256 + (xx&1)*128 + c;
  pcl[(((size_t)b*66 + yy+1)*66 + xx+1)*128 + c] = f2bf(x[((size_t)b*1024 + n)*512 + f]);
}

// mask [48][64][64] int -> rm [48][1024] u8 (2x2 any)
__global__ __launch_bounds__(256) void k_rmask(const int* __restrict__ mask, unsigned char* __restrict__ rm){
  int idx = blockIdx.x*256 + threadIdx.x;
  if(idx >= 48*1024) return;
  const int m = idx >> 10, n = idx & 1023; const int h = n>>5, w = n&31;
  const int* mp = mask + ((size_t)m*64 + h*2)*64 + w*2;
  rm[idx] = (unsigned char)((mp[0]==1) | (mp[1]==1) | (mp[64]==1) | (mp[65]==1));
}

// v [64 bh][1024 n][64 d] -> vt [64 bh][64 d][1024 n]
__global__ __launch_bounds__(256) void k_vt(const u16* __restrict__ v, u16* __restrict__ vt){
  const int nt = blockIdx.x, bh = blockIdx.y;
  __shared__ u16 t[64][72];
  const int tid = threadIdx.x;
  const int i = tid>>2, cq = tid&3;
  const u16* src = v + ((size_t)bh*1024 + nt*64 + i)*64 + cq*16;
  const short8 s0 = *(const short8*)src;
  const short8 s1 = *(const short8*)(src+8);
  #pragma unroll
  for(int e=0;e<8;e++){ t[cq*16+e][i] = (u16)s0[e]; t[cq*16+8+e][i] = (u16)s1[e]; }
  __syncthreads();
  short8 o0, o1;
  #pragma unroll
  for(int e=0;e<8;e++){ o0[e] = (short)t[i][cq*16+e]; o1[e] = (short)t[i][cq*16+8+e]; }
  u16* dst = vt + (size_t)bh*65536 + (size_t)i*1024 + nt*64 + cq*16;
  *(short8*)dst = o0;
  *(short8*)(dst+8) = o1;
}

// ---------------- layernorm (wave per token) ----------------
__global__ __launch_bounds__(256) void k_ln_bf(const float* __restrict__ in, const float* __restrict__ gw,
                                               const float* __restrict__ bw, u16* __restrict__ out){
  const int tok = blockIdx.x*4 + (threadIdx.x>>6);
  const int lane = threadIdx.x & 63;
  const float* rp = in + (size_t)tok*512 + lane*8;
  const float4 a = *(const float4*)rp;
  const float4 b = *(const float4*)(rp+4);
  float s  = a.x+a.y+a.z+a.w + b.x+b.y+b.z+b.w;
  float sq = a.x*a.x+a.y*a.y+a.z*a.z+a.w*a.w + b.x*b.x+b.y*b.y+b.z*b.z+b.w*b.w;
  #pragma unroll
  for(int off=1; off<64; off<<=1){ s += __shfl_xor(s,off); sq += __shfl_xor(sq,off); }
  const float mu = s*(1.f/512.f);
  const float rs = rsqrtf(sq*(1.f/512.f) - mu*mu + 1e-5f);
  const float4 g0 = *(const float4*)(gw + lane*8);
  const float4 g1 = *(const float4*)(gw + lane*8 + 4);
  const float4 b0 = *(const float4*)(bw + lane*8);
  const float4 b1 = *(const float4*)(bw + lane*8 + 4);
  short8 o8;
  o8[0]=f2bf((a.x-mu)*rs*g0.x+b0.x); o8[1]=f2bf((a.y-mu)*rs*g0.y+b0.y);
  o8[2]=f2bf((a.z-mu)*rs*g0.z+b0.z); o8[3]=f2bf((a.w-mu)*rs*g0.w+b0.w);
  o8[4]=f2bf((b.x-mu)*rs*g1.x+b1.x); o8[5]=f2bf((b.y-mu)*rs*g1.y+b1.y);
  o8[6]=f2bf((b.z-mu)*rs*g1.z+b1.z); o8[7]=f2bf((b.w-mu)*rs*g1.w+b1.w);
  *(short8*)(out + (size_t)tok*512 + lane*8) = o8;
}

// LN + sincos 2d posemb -> f32 x (wave per token)
__global__ __launch_bounds__(256) void k_lnq_pos(const float* __restrict__ in, const float* __restrict__ gw,
                                                 const float* __restrict__ bw, float* __restrict__ out){
  const int tok = blockIdx.x*4 + (threadIdx.x>>6);
  const int lane = threadIdx.x & 63;
  const float* rp = in + (size_t)tok*512 + lane*8;
  const float4 a = *(const float4*)rp;
  const float4 b = *(const float4*)(rp+4);
  float s  = a.x+a.y+a.z+a.w + b.x+b.y+b.z+b.w;
  float sq = a.x*a.x+a.y*a.y+a.z*a.z+a.w*a.w + b.x*b.x+b.y*b.y+b.z*b.z+b.w*b.w;
  #pragma unroll
  for(int off=1; off<64; off<<=1){ s += __shfl_xor(s,off); sq += __shfl_xor(sq,off); }
  const float mu = s*(1.f/512.f);
  const float rs = rsqrtf(sq*(1.f/512.f) - mu*mu + 1e-5f);
  const int n = tok & 1023; const int yy = n>>5, xx = n&31;
  const int f0 = lane*8; const int sec = f0>>7;
  const float coord = (sec<2) ? (float)xx : (float)yy;
  const float vv[8] = {a.x,a.y,a.z,a.w,b.x,b.y,b.z,b.w};
  float ov[8];
  #pragma unroll
  for(int j=0;j<8;j++){
    const int f = f0+j; const int qq = f & 127;
    const float om = __expf(-(float)qq * (9.2103403719761836f/127.f));
    const float arg = coord * om;
    const float pe = (sec&1) ? __cosf(arg) : __sinf(arg);
    ov[j] = (vv[j]-mu)*rs*gw[f] + bw[f] + pe;
  }
  float* op = out + (size_t)tok*512 + f0;
  *(float4*)op = (float4){ov[0],ov[1],ov[2],ov[3]};
  *(float4*)(op+4) = (float4){ov[4],ov[5],ov[6],ov[7]};
}

// ---------------- GEMM (64x64 tile, BK=64, 4 waves, dbuf prefetch, swizzled LDS) ----------------
// EPI: 0 proj(f32+bias) 1 qkv-scatter(bf16) 2 resid(f32) 3 gelu(bf16+bias) 4 resid+bias 5 conv1->patches 6 conv2->out
template<int EPI, int CONVC>
__global__ __launch_bounds__(256, 4)
void k_gemm(const u16* __restrict__ A, const u16* __restrict__ Wt,
            const float* __restrict__ bias, void* __restrict__ outp,
            const float* __restrict__ resid, int M, int N, int Kd)
{
  __shared__ u16 Ald[2][4096];
  __shared__ u16 Bld[2][4096];
  const int tid = threadIdx.x, lane = tid & 63, wv = tid >> 6;
  const int lr = lane & 15, g = lane >> 4;
  const int m0 = blockIdx.x * 64, n0 = blockIdx.y * 64;
  const int wm = (wv >> 1) * 32, wn = (wv & 1) * 32;
  // staging: thread covers (row=tid>>3 [+32], 16B chunk (tid&7)^(row&7)), linear LDS dest tid*16B
  const int srow = tid >> 3;
  const int sc  = (tid & 7) ^ (srow & 7);      // (srow+32)&7 == srow&7
  int b0=0, yy0=0, xx0=0;
  if constexpr (CONVC != 0){ b0 = m0>>12; yy0 = (m0>>6)&63; }
  const u16* arow0p; const u16* arow1p;
  if constexpr (CONVC != 0){
    arow0p = A; arow1p = A;                    // bases resolved per-iter with tap
  } else {
    arow0p = A + (size_t)(m0+srow)*Kd + sc*8;
    arow1p = A + (size_t)(m0+srow+32)*Kd + sc*8;
  }
  const u16* brow0p = Wt + (size_t)(n0+srow)*Kd + sc*8;
  const u16* brow1p = Wt + (size_t)(n0+srow+32)*Kd + sc*8;

  f32x4 acc[2][2];
  #pragma unroll
  for(int i=0;i<2;i++)
    #pragma unroll
    for(int j=0;j<2;j++) acc[i][j] = (f32x4){0.f,0.f,0.f,0.f};

  const int nIter = Kd >> 6;
  int cur = 0;

  auto stage = [&](int kt, int buf){
    const int k0 = kt << 6;
    const u16 *ga0, *ga1;
    if constexpr (CONVC != 0){
      const int tap = k0 / CONVC;
      const int ic0 = k0 - tap*CONVC;
      const int ky = tap/3, kx = tap - 3*(tap/3);
      const size_t rb0 = ((size_t)((b0*66 + yy0+ky)*66 + kx))*CONVC + ic0 + sc*8;
      ga0 = A + rb0 + (size_t)(srow)*CONVC;
      ga1 = A + rb0 + (size_t)(srow+32)*CONVC;
    } else {
      ga0 = arow0p + k0;
      ga1 = arow1p + k0;
    }
    gload16(ga0, &Ald[buf][tid*8]);
    gload16(ga1, &Ald[buf][2048 + tid*8]);
    gload16(brow0p + k0, &Bld[buf][tid*8]);
    gload16(brow1p + k0, &Bld[buf][2048 + tid*8]);
  };

  stage(0, 0);
  for(int kt=0; kt<nIter; ++kt){
    __syncthreads();                       // drains stage(kt); barrier
    if(kt+1 < nIter) stage(kt+1, cur^1);   // flies under compute below
    short8 af[2][2], bg[2][2];
    #pragma unroll
    for(int mi=0;mi<2;mi++)
      #pragma unroll
      for(int kk=0;kk<2;kk++){
        const int R = wm + mi*16 + lr;
        const int Rn = wn + mi*16 + lr;
        const int c = kk*4 + g;
        af[mi][kk] = *(const short8*)&Ald[cur][R*64 + ((c ^ (R&7))<<3)];
        bg[mi][kk] = *(const short8*)&Bld[cur][Rn*64 + ((c ^ (Rn&7))<<3)];
      }
    #pragma unroll
    for(int mi=0;mi<2;mi++)
      #pragma unroll
      for(int nj=0;nj<2;nj++)
        #pragma unroll
        for(int kk=0;kk<2;kk++)
          acc[mi][nj] = mfma16(af[mi][kk], bg[nj][kk], acc[mi][nj]);
    cur ^= 1;
  }

  #pragma unroll
  for(int mi=0;mi<2;mi++){
    #pragma unroll
    for(int nj=0;nj<2;nj++){
      #pragma unroll
      for(int r=0;r<4;r++){
        const int mrow = m0 + wm + mi*16 + g*4 + r;
        const int ncol = n0 + wn + nj*16 + lr;
        float val = acc[mi][nj][r];
        if constexpr (EPI==0 || EPI==3 || EPI==4 || EPI==5 || EPI==6)
          val += bias[ncol];
        if constexpr (EPI==0){
          ((float*)outp)[(size_t)mrow*512 + ncol] = val;
        } else if constexpr (EPI==1){
          const int sec = ncol >> 9, rem = ncol & 511;
          const int head = rem >> 6, d = rem & 63;
          const int b = mrow >> 10, t = mrow & 1023;
          ((u16*)outp)[(size_t)sec*4194304 + ((size_t)((b*8+head)*1024 + t))*64 + d] = f2bf(val);
        } else if constexpr (EPI==2 || EPI==4){
          const size_t idx = (size_t)mrow*512 + ncol;
          ((float*)outp)[idx] = resid[idx] + val;
        } else if constexpr (EPI==3){
          const float gl = 0.5f * val * (1.f + erff(val * 0.70710678118654752f));
          ((u16*)outp)[(size_t)mrow*512 + ncol] = f2bf(gl);
        } else if constexpr (EPI==5){
          const int b = mrow>>12; const int rr = mrow&4095; const int y = rr>>6; const int xx = rr&63;
          const size_t pidx = ((size_t)(b*1024 + (y>>1)*32 + (xx>>1)))*512 + (y&1)*256 + (xx&1)*128 + ncol;
          ((float*)outp)[pidx] = val;
        } else if constexpr (EPI==6){
          const int b = mrow>>12; const int rr = mrow&4095; const int y = rr>>6; const int xx = rr&63;
          ((float*)outp)[(((size_t)(b*320 + ncol))*64 + y)*64 + xx] = val;
        }
      }
    }
  }
}

// ---------------- attention pass A: global min of scaled dots ----------------
__global__ __launch_bounds__(256, 4)
void k_attn_min(const u16* __restrict__ q, const u16* __restrict__ k, u32* __restrict__ minbuf, int layer){
  const int qt = blockIdx.x, bh = blockIdx.y;
  __shared__ u16 Kld[2][4096];
  __shared__ float red[4];
  const int tid = threadIdx.x, lane = tid & 63, wv = tid >> 6;
  const int lr = lane & 15, g = lane >> 4;
  const u16* qp = q + ((size_t)bh*1024 + qt*64 + wv*16 + lr)*64;
  const short8 qa0 = *(const short8*)(qp + g*8);
  const short8 qa1 = *(const short8*)(qp + 32 + g*8);
  const u16* kbase = k + (size_t)bh*65536;
  const int srow = ((wv*64 + lane)>>3), scs = lane&7;
  const int scg = scs ^ (srow&7);
  const int srow2 = srow + 32;
  const int scg2 = scs ^ (srow2&7);
  float mn = 3.0e38f;
  // prologue stage jt=0
  gload16(kbase + (size_t)srow*64 + scg*8, &Kld[0][wv*512]);
  gload16(kbase + (size_t)srow2*64 + scg2*8, &Kld[0][2048 + wv*512]);
  int cur = 0;
  for(int jt=0; jt<16; ++jt){
    __syncthreads();
    if(jt < 15){
      const int j1 = (jt+1)*64;
      gload16(kbase + (size_t)(j1+srow)*64 + scg*8, &Kld[cur^1][wv*512]);
      gload16(kbase + (size_t)(j1+srow2)*64 + scg2*8, &Kld[cur^1][2048 + wv*512]);
    }
    #pragma unroll
    for(int c=0;c<4;c++){
      const int rr = c*16 + lr;
      const short8 kb0 = *(const short8*)&Kld[cur][rr*64 + ((g ^ (rr&7))<<3)];
      const short8 kb1 = *(const short8*)&Kld[cur][rr*64 + (((g+4) ^ (rr&7))<<3)];
      f32x4 s4 = (f32x4){0.f,0.f,0.f,0.f};
      s4 = mfma16(qa0, kb0, s4);
      s4 = mfma16(qa1, kb1, s4);
      mn = fminf(mn, fminf(fminf(s4[0],s4[1]), fminf(s4[2],s4[3])));
    }
    cur ^= 1;
  }
  mn *= 0.125f;
  #pragma unroll
  for(int off=32; off; off>>=1) mn = fminf(mn, __shfl_down(mn, off));
  if(lane==0) red[wv] = mn;
  __syncthreads();
  if(tid==0){
    const float m2 = fminf(fminf(red[0],red[1]), fminf(red[2],red[3]));
    atomicMin(minbuf + layer, fkey(m2));
  }
}

// ---------------- attention pass B: flash with mask + min_val ----------------
__global__ __launch_bounds__(256, 4)
void k_attn(const u16* __restrict__ q, const u16* __restrict__ k, const u16* __restrict__ vt,
            const unsigned char* __restrict__ rm, const u32* __restrict__ minbuf,
            u16* __restrict__ o, int layer){
  const int qt = blockIdx.x, bh = blockIdx.y; const int b = bh>>3, h = bh&7;
  __shared__ u16 Kld[2][4096];
  __shared__ u16 Vtld[2][4096];
  __shared__ u16 Pld[4][1024];
  const int tid = threadIdx.x, lane = tid & 63, wv = tid >> 6;
  const int lr = lane & 15, g = lane >> 4;
  const u16* qp = q + ((size_t)bh*1024 + qt*64 + wv*16 + lr)*64;
  const short8 qa0 = *(const short8*)(qp + g*8);
  const short8 qa1 = *(const short8*)(qp + 32 + g*8);
  const float SC = 0.125f * 1.44269504088896f;           // scale * log2(e)
  const float minv = funkey(minbuf[layer]) * 1.44269504088896f;
  const unsigned char* rmp = rm + (size_t)(layer*8 + b)*1024;
  bool rrow[4];
  #pragma unroll
  for(int r=0;r<4;r++) rrow[r] = rmp[qt*64 + wv*16 + g*4 + r] != 0;
  float mrun[4], lrun[4];
  #pragma unroll
  for(int r=0;r<4;r++){ mrun[r] = -3.0e38f; lrun[r] = 0.f; }
  f32x4 accd[4];
  #pragma unroll
  for(int d=0;d<4;d++) accd[d] = (f32x4){0.f,0.f,0.f,0.f};
  const u16* kbase = k + (size_t)bh*65536;
  const u16* vtbase = vt + (size_t)bh*65536;
  const int srow = ((wv*64 + lane)>>3), scs = lane&7;
  const int scg = scs ^ (srow&7);
  const int srow2 = srow + 32;
  const int scg2 = scs ^ (srow2&7);
  // prologue: stage jt=0
  gload16(kbase + (size_t)srow*64 + scg*8, &Kld[0][wv*512]);
  gload16(kbase + (size_t)srow2*64 + scg2*8, &Kld[0][2048 + wv*512]);
  gload16(vtbase + (size_t)srow*1024 + scg*8, &Vtld[0][wv*512]);
  gload16(vtbase + (size_t)srow2*1024 + scg2*8, &Vtld[0][2048 + wv*512]);
  int cur = 0;
  for(int jt=0; jt<16; ++jt){
    const int j0 = jt*64;
    __syncthreads();                       // staging for cur complete
    if(jt < 15){
      const int j1 = j0 + 64;
      gload16(kbase + (size_t)(j1+srow)*64 + scg*8, &Kld[cur^1][wv*512]);
      gload16(kbase + (size_t)(j1+srow2)*64 + scg2*8, &Kld[cur^1][2048 + wv*512]);
      gload16(vtbase + (size_t)srow*1024 + j1 + scg*8, &Vtld[cur^1][wv*512]);
      gload16(vtbase + (size_t)srow2*1024 + j1 + scg2*8, &Vtld[cur^1][2048 + wv*512]);
    }
    // QK^T (scores in exp2 domain)
    float p4[4][4];
    #pragma unroll
    for(int c=0;c<4;c++){
      const int rr = c*16 + lr;
      const short8 kb0 = *(const short8*)&Kld[cur][rr*64 + ((g ^ (rr&7))<<3)];
      const short8 kb1 = *(const short8*)&Kld[cur][rr*64 + (((g+4) ^ (rr&7))<<3)];
      f32x4 s4 = (f32x4){0.f,0.f,0.f,0.f};
      s4 = mfma16(qa0, kb0, s4);
      s4 = mfma16(qa1, kb1, s4);
      const bool colok = rmp[j0 + rr] != 0;
      #pragma unroll
      for(int r=0;r<4;r++){
        float vl = s4[r]*SC;
        if(!(rrow[r] || colok)) vl = minv;
        p4[c][r] = vl;
      }
    }
    // online softmax (exp2 domain)
    float sf[4];
    #pragma unroll
    for(int r=0;r<4;r++){
      float mx = fmaxf(fmaxf(p4[0][r],p4[1][r]), fmaxf(p4[2][r],p4[3][r]));
      mx = fmaxf(mx, __shfl_xor(mx,1)); mx = fmaxf(mx, __shfl_xor(mx,2));
      mx = fmaxf(mx, __shfl_xor(mx,4)); mx = fmaxf(mx, __shfl_xor(mx,8));
      const float mnew = fmaxf(mrun[r], mx);
      float ts = 0.f;
      #pragma unroll
      for(int c=0;c<4;c++){ const float e = exp2f(p4[c][r]-mnew); p4[c][r] = e; ts += e; }
      ts += __shfl_xor(ts,1); ts += __shfl_xor(ts,2); ts += __shfl_xor(ts,4); ts += __shfl_xor(ts,8);
      sf[r] = exp2f(mrun[r] - mnew);
      lrun[r] = lrun[r]*sf[r] + ts;
      mrun[r] = mnew;
    }
    #pragma unroll
    for(int d=0;d<4;d++)
      #pragma unroll
      for(int r=0;r<4;r++) accd[d][r] *= sf[r];
    // P -> LDS (per-wave, chunk-swizzled)
    #pragma unroll
    for(int c=0;c<4;c++)
      #pragma unroll
      for(int r=0;r<4;r++){
        const int ql = g*4+r, cl = c*16+lr;
        Pld[wv][ql*64 + ((((cl>>3) ^ (ql&7))<<3) | (cl&7))] = f2bf(p4[c][r]);
      }
    const short8 pa0 = *(const short8*)&Pld[wv][lr*64 + ((g ^ (lr&7))<<3)];
    const short8 pa1 = *(const short8*)&Pld[wv][lr*64 + (((g+4) ^ (lr&7))<<3)];
    // PV
    #pragma unroll
    for(int d=0;d<4;d++){
      const int rr = d*16 + lr;
      const short8 vb0 = *(const short8*)&Vtld[cur][rr*64 + ((g ^ (rr&7))<<3)];
      const short8 vb1 = *(const short8*)&Vtld[cur][rr*64 + (((g+4) ^ (rr&7))<<3)];
      accd[d] = mfma16(pa0, vb0, accd[d]);
      accd[d] = mfma16(pa1, vb1, accd[d]);
    }
    cur ^= 1;
  }
  #pragma unroll
  for(int d=0;d<4;d++)
    #pragma unroll
    for(int r=0;r<4;r++){
      const int qrow = qt*64 + wv*16 + g*4 + r;
      o[((size_t)b*1024 + qrow)*512 + h*64 + d*16 + lr] = f2bf(accd[d][r] / lrun[r]);
    }
}

// ---------------- host ----------------
extern "C" void kernel_launch(void* const* d_in, const int* in_sizes, int n_in,
                              void* d_out, int out_size, void* d_ws, size_t ws_size,
                              hipStream_t stream)
{
  const float* img     = (const float*)d_in[0];
  const int*   mask    = (const int*)d_in[1];
  const float* conv1_w = (const float*)d_in[2];
  const float* conv1_b = (const float*)d_in[3];
  const float* ln_p_g  = (const float*)d_in[4];
  const float* ln_p_b  = (const float*)d_in[5];
  const float* proj_w  = (const float*)d_in[6];
  const float* proj_b  = (const float*)d_in[7];
  const float* ln_q_g  = (const float*)d_in[8];
  const float* ln_q_b  = (const float*)d_in[9];
  const float* attn_ln_g = (const float*)d_in[10];
  const float* attn_ln_b = (const float*)d_in[11];
  const float* wqkv    = (const float*)d_in[12];
  const float* wo      = (const float*)d_in[13];
  const float* ff_ln_g = (const float*)d_in[14];
  const float* ff_ln_b = (const float*)d_in[15];
  const float* w1      = (const float*)d_in[16];
  const float* b1      = (const float*)d_in[17];
  const float* w2      = (const float*)d_in[18];
  const float* b2      = (const float*)d_in[19];
  const float* conv2_w = (const float*)d_in[20];
  const float* conv2_b = (const float*)d_in[21];

  if(ws_size < WS_NEED) return;
  char* ws = (char*)d_ws;
  u16* projWt = (u16*)(ws + O_PROJW);
  u16* qkvWt  = (u16*)(ws + O_QKVW);
  u16* woWt   = (u16*)(ws + O_WOW);
  u16* w1Wt   = (u16*)(ws + O_W1W);
  u16* w2Wt   = (u16*)(ws + O_W2W);
  u16* c1Wt   = (u16*)(ws + O_C1W);
  u16* c2Wt   = (u16*)(ws + O_C2W);
  u16* pcl    = (u16*)(ws + O_RA);      // pcl1 / vt / pcl2
  float* tmpf = (float*)(ws + O_RA);    // proj out (after pcl1 dead)
  u16* vtb    = (u16*)(ws + O_RA);      // v^T during layer loop
  float* patches = (float*)(ws + O_RB);
  u16* qkvb   = (u16*)(ws + O_RB);      // q|k|v, each 8*8*1024*64
  float* xbuf = (float*)(ws + O_X);
  u16* xnbf   = (u16*)(ws + O_D);
  u16* obf    = (u16*)(ws + O_F);
  unsigned char* rmb = (unsigned char*)(ws + O_RM);
  u32* minbuf = (u32*)(ws + O_MIN);

  hipMemsetAsync(ws + O_MIN, 0xFF, 64, stream);
  hipMemsetAsync(ws + O_RA, 0, 22302720, stream);   // pcl1 zero borders

  // weight conversion
  k_transpose_bf<<<dim3(16,16,1),256,0,stream>>>(proj_w, projWt, 512, 512);
  k_transpose_bf<<<dim3(16,48,6),256,0,stream>>>(wqkv,   qkvWt,  512, 1536);
  k_transpose_bf<<<dim3(16,16,6),256,0,stream>>>(wo,     woWt,   512, 512);
  k_transpose_bf<<<dim3(16,16,6),256,0,stream>>>(w1,     w1Wt,   512, 512);
  k_transpose_bf<<<dim3(16,16,6),256,0,stream>>>(w2,     w2Wt,   512, 512);
  k_convw<<<1440,256,0,stream>>>(conv1_w, c1Wt, 128, 320);
  k_convw<<<1440,256,0,stream>>>(conv2_w, c2Wt, 320, 128);
  k_rmask<<<192,256,0,stream>>>(mask, rmb);

  // patch embed
  k_pad_img<<<dim3(512,5),256,0,stream>>>(img, pcl);
  k_gemm<5,320><<<dim3(512,2),256,0,stream>>>(pcl, c1Wt, conv1_b, patches, nullptr, 32768, 128, 2880);
  k_ln_bf<<<2048,256,0,stream>>>(patches, ln_p_g, ln_p_b, xnbf);
  k_gemm<0,0><<<dim3(128,8),256,0,stream>>>(xnbf, projWt, proj_b, tmpf, nullptr, 8192, 512, 512);
  k_lnq_pos<<<2048,256,0,stream>>>(tmpf, ln_q_g, ln_q_b, xbuf);

  const u16* qb = qkvb;
  const u16* kb = qkvb + 4194304;
  const u16* vb = qkvb + 8388608;
  for(int i=0;i<6;i++){
    k_ln_bf<<<2048,256,0,stream>>>(xbuf, attn_ln_g + i*512, attn_ln_b + i*512, xnbf);
    k_gemm<1,0><<<dim3(128,24),256,0,stream>>>(xnbf, qkvWt + (size_t)i*1536*512, nullptr, qkvb, nullptr, 8192, 1536, 512);
    k_vt<<<dim3(16,64),256,0,stream>>>(vb, vtb);
    k_attn_min<<<dim3(16,64),256,0,stream>>>(qb, kb, minbuf, i);
    k_attn<<<dim3(16,64),256,0,stream>>>(qb, kb, vtb, rmb, minbuf, obf, i);
    k_gemm<2,0><<<dim3(128,8),256,0,stream>>>(obf, woWt + (size_t)i*512*512, nullptr, xbuf, xbuf, 8192, 512, 512);
    k_ln_bf<<<2048,256,0,stream>>>(xbuf, ff_ln_g + i*512, ff_ln_b + i*512, xnbf);
    k_gemm<3,0><<<dim3(128,8),256,0,stream>>>(xnbf, w1Wt + (size_t)i*512*512, b1 + i*512, obf, nullptr, 8192, 512, 512);
    k_gemm<4,0><<<dim3(128,8),256,0,stream>>>(obf, w2Wt + (size_t)i*512*512, b2 + i*512, xbuf, xbuf, 8192, 512, 512);
  }

  // final conv
  hipMemsetAsync(ws + O_RA, 0, 8921088, stream);    // pcl2 zero borders
  k_pad_tok<<<16384,256,0,stream>>>(xbuf, pcl);
  k_gemm<6,128><<<dim3(512,5),256,0,stream>>>(pcl, c2Wt, conv2_b, d_out, nullptr, 32768, 320, 1152);
}